// Round 10
// baseline (172.785 us; speedup 1.0000x reference)
//
#include <hip/hip_runtime.h>

#define Bz   32
#define Nn   1024
#define Dd   128
#define OUTW 64
#define CEXP 0.72134752044448169f   // 0.5 * log2(e)
#define LOG2E 1.4426950408889634f

typedef __attribute__((ext_vector_type(8))) short bf16x8;   // 8 bf16 = 4 VGPR
typedef __attribute__((ext_vector_type(4))) short bf16x4;
typedef __attribute__((ext_vector_type(4))) float f32x4;
typedef __attribute__((ext_vector_type(16))) float f32x16;

static __device__ __forceinline__ unsigned short f2bf(float x) {
    unsigned u = __float_as_uint(x);
    u += 0x7FFFu + ((u >> 16) & 1u);            // RNE
    return (unsigned short)(u >> 16);
}
static __device__ __forceinline__ float bf2f(short b) {
    return __uint_as_float(((unsigned)(unsigned short)b) << 16);
}
static __device__ __forceinline__ unsigned cvt_pk_bf16(float lo, float hi) {
    unsigned r;
    asm("v_cvt_pk_bf16_f32 %0, %1, %2" : "=v"(r) : "v"(lo), "v"(hi));
    return r;
}
// a[32+i] <-> b[i] halves exchange (T12 recipe ordering)
#define PLSWAP(a, b) asm("v_permlane32_swap_b32 %0, %1" : "+v"(a), "+v"(b))

// async global->LDS, 16B per lane; LDS dest = wave-uniform base + lane*16
#define GLL16(g, l) __builtin_amdgcn_global_load_lds( \
    (const __attribute__((address_space(1))) unsigned*)(const void*)(g), \
    (__attribute__((address_space(3))) unsigned*)(void*)(l), 16, 0, 0)
#define WAITVN(n) { asm volatile("s_waitcnt vmcnt(" #n ")" ::: "memory"); \
                    __builtin_amdgcn_sched_barrier(0); }
#define SBAR() __builtin_amdgcn_s_barrier()

// Global bf16 arrays carry a T2 swizzle: element [n][d] stored at
// [n][d ^ ((n&7)*8)] (row-major) / [d][kv ^ ((d&7)*8)] within each 64-aligned
// kv window (transposed). XOR acts on 16B chunks -> vector ops stay aligned.

// ---------------------------------------------------------------------------
// Kernel 1: L2-normalize + swizzled bf16 row-major AND transposed copies.
// 4 lanes per row (32 contiguous floats each): norm reduce = 2 shfl_xor.
__global__ __launch_bounds__(256) void k_norm(const float* __restrict__ drug1,
                                              const float* __restrict__ drug2,
                                              short* __restrict__ d1s,
                                              short* __restrict__ d2s,
                                              short* __restrict__ d1ts,
                                              short* __restrict__ d2ts) {
    __shared__ __attribute__((aligned(16))) short T[Dd * 64];   // 16 KB
    const int tid = threadIdx.x;
    const int b = blockIdx.y;
    const int n0 = blockIdx.x * 64;
    const float* src; short* dstR; short* dstT;
    if (blockIdx.z == 0) { src = drug1; dstR = d1s; dstT = d1ts; }
    else                 { src = drug2; dstR = d2s; dstT = d2ts; }

    const int r64 = tid >> 2;          // row within tile (0..63)
    const int q4  = tid & 3;           // d-quarter (32 floats)
    const int n = n0 + r64;
    const float* rp = src + ((long)b * Nn + n) * Dd + q4 * 32;
    float x[32];
    #pragma unroll
    for (int k = 0; k < 8; ++k) {
        const float4 v = *(const float4*)(rp + k * 4);
        x[k*4+0] = v.x; x[k*4+1] = v.y; x[k*4+2] = v.z; x[k*4+3] = v.w;
    }
    float ss = 0.f;
    #pragma unroll
    for (int e = 0; e < 32; ++e) ss += x[e] * x[e];
    ss += __shfl_xor(ss, 1, 64);       // quad = the 4 lanes of this row
    ss += __shfl_xor(ss, 2, 64);
    const float inv = 1.0f / fmaxf(sqrtf(ss), 1e-12f);
    // pack to bf16 pairs once; both copies reuse the same bits
    unsigned pk16[16];
    #pragma unroll
    for (int k = 0; k < 16; ++k)
        pk16[k] = cvt_pk_bf16(x[2*k] * inv, x[2*k+1] * inv);
    // swizzled row-major store: 4 x 16B chunks at chunk^(n&7)
    short* wr = dstR + ((long)b * Nn + n) * Dd;
    #pragma unroll
    for (int k = 0; k < 4; ++k) {
        uint4 w;
        w.x = pk16[k*4+0]; w.y = pk16[k*4+1];
        w.z = pk16[k*4+2]; w.w = pk16[k*4+3];
        *(uint4*)(wr + (((q4 * 4 + k) ^ (n & 7)) * 8)) = w;
    }
    // transposed LDS fill; Csw keeps the 4 q4-groups on disjoint bank sets
    #pragma unroll
    for (int e = 0; e < 32; ++e) {
        const int d = q4 * 32 + e;
        const int Csw = (16 * q4) ^ (8 * ((e >> 2) & 3));
        const unsigned v = (e & 1) ? (pk16[e >> 1] >> 16) : pk16[e >> 1];
        T[d * 64 + (r64 ^ Csw)] = (short)(unsigned short)v;
    }
    __syncthreads();
    // b128 reads of transposed rows; global store at swizzled group gi^(d&7)
    const int d = tid >> 1, h = tid & 1;
    const int C = (16 * (d >> 5)) ^ (8 * ((d >> 2) & 3));
    short* wtp = dstT + ((long)b * Dd + d) * Nn + n0;
    #pragma unroll
    for (int k = 0; k < 4; ++k) {
        const int gi = h * 4 + k;
        *(bf16x8*)(wtp + ((gi ^ (d & 7)) * 8)) =
            *(const bf16x8*)&T[d * 64 + ((gi * 8) ^ C)];
    }
}

// ---------------------------------------------------------------------------
// Kernel 2: dual-direction attention, 32x32x16 MFMA + permlane P-routing.
// (unchanged from round 8 — 54.6us control)
__global__ __launch_bounds__(256, 2) void k_attn(const short* __restrict__ d1s,
                                                 const short* __restrict__ d2s,
                                                 const short* __restrict__ d1ts,
                                                 const short* __restrict__ d2ts,
                                                 short* __restrict__ layerA,
                                                 short* __restrict__ layerB) {
    __shared__ __attribute__((aligned(16))) short Kl[2][64][128];  // 32 KB
    __shared__ __attribute__((aligned(16))) short Vl[2][128][64];  // 32 KB

    const int bid = blockIdx.x;            // XCD-aware remap (proven r3)
    const int xcd = bid & 7, tt = bid >> 3;
    const int jq = tt & 7, gq = tt >> 3;
    const int grp = xcd + 8 * gq;          // (b, z)
    const int b = grp & 31, z = grp >> 5;

    const int tid = threadIdx.x, wave = tid >> 6, lane = tid & 63;
    const int r31 = lane & 31, h8 = lane >> 5, r7 = lane & 7;
    const short *Q, *Ks, *Vts; short* O;
    if (z == 0) { Q = d1s; Ks = d2s; Vts = d2ts; O = layerA; }
    else        { Q = d2s; Ks = d1s; Vts = d1ts; O = layerB; }
    const int q0 = jq * 128 + wave * 32;

    // Q B-frags: lane holds Q[q0+r31][c*16 + h8*8 + j] (de-swizzled)
    const short* Qb = Q + ((long)b * Nn + q0) * Dd;
    bf16x8 qf[8];
    #pragma unroll
    for (int c = 0; c < 8; ++c)
        qf[c] = *(const bf16x8*)(Qb + (long)r31 * Dd + (((2 * c + h8) ^ r7) * 8));

    f32x16 oacc[4];
    #pragma unroll
    for (int dblk = 0; dblk < 4; ++dblk)
        #pragma unroll
        for (int r = 0; r < 16; ++r) oacc[dblk][r] = 0.f;
    float lsum = 0.f;

    const short* Ksb = Ks  + (long)b * Nn * Dd;
    const short* Vtb = Vts + (long)b * Dd * Nn;
    const int klr = lane >> 4, klc = lane & 15;
    const int vlr = lane >> 3, vlc = lane & 7;

    auto STAGE = [&](int buf, int tile) {
        const int kv0 = tile * 64;
        #pragma unroll
        for (int j = 0; j < 4; ++j)
            GLL16(Ksb + ((long)(kv0 + wave * 16 + j * 4 + klr)) * Dd + klc * 8,
                  &Kl[buf][wave * 16 + j * 4][0]);
        #pragma unroll
        for (int j = 0; j < 4; ++j)
            GLL16(Vtb + ((long)(wave * 32 + j * 8 + vlr)) * Nn + kv0 + vlc * 8,
                  &Vl[buf][wave * 32 + j * 8][0]);
    };

    auto SUB = [&](int buf, int sub) {
        // ---- S' = K·Q^T (32 kv x 32 q), D: lane holds 16 kv for q=r31 ----
        f32x16 st;
        #pragma unroll
        for (int r = 0; r < 16; ++r) st[r] = 0.f;
        __builtin_amdgcn_s_setprio(1);
        #pragma unroll
        for (int c = 0; c < 8; ++c) {
            const bf16x8 kf = *(const bf16x8*)
                &Kl[buf][sub * 32 + r31][((2 * c + h8) ^ r7) * 8];
            st = __builtin_amdgcn_mfma_f32_32x32x16_bf16(kf, qf[c], st, 0, 0, 0);
        }
        __builtin_amdgcn_s_setprio(0);
        // ---- V B-frags (issue early; latency hides under softmax VALU) ----
        bf16x8 vf[2][4];
        #pragma unroll
        for (int kvh = 0; kvh < 2; ++kvh)
            #pragma unroll
            for (int dblk = 0; dblk < 4; ++dblk)
                vf[kvh][dblk] = *(const bf16x8*)
                    &Vl[buf][dblk * 32 + r31][((4 * sub + 2 * kvh + h8) ^ r7) * 8];
        // ---- P = exp(0.5*S); in-lane row-sum; pack+permlane to A-frags ----
        float p[16];
        #pragma unroll
        for (int r = 0; r < 16; ++r) p[r] = exp2f(st[r] * CEXP);
        float s4[4];
        #pragma unroll
        for (int k = 0; k < 4; ++k)
            s4[k] = (p[4 * k] + p[4 * k + 1]) + (p[4 * k + 2] + p[4 * k + 3]);
        lsum += (s4[0] + s4[1]) + (s4[2] + s4[3]);
        unsigned u0 = cvt_pk_bf16(p[0], p[1]),  u1 = cvt_pk_bf16(p[2], p[3]);
        unsigned u2 = cvt_pk_bf16(p[4], p[5]),  u3 = cvt_pk_bf16(p[6], p[7]);
        unsigned u4 = cvt_pk_bf16(p[8], p[9]),  u5 = cvt_pk_bf16(p[10], p[11]);
        unsigned u6 = cvt_pk_bf16(p[12], p[13]), u7 = cvt_pk_bf16(p[14], p[15]);
        PLSWAP(u0, u2); PLSWAP(u1, u3);   // frag0: kv sub*32 + 0..15
        PLSWAP(u4, u6); PLSWAP(u5, u7);   // frag1: kv sub*32 + 16..31
        union { unsigned u[4]; bf16x8 v; } f0, f1;
        f0.u[0] = u0; f0.u[1] = u1; f0.u[2] = u2; f0.u[3] = u3;
        f1.u[0] = u4; f1.u[1] = u5; f1.u[2] = u6; f1.u[3] = u7;
        // ---- O += P·V ----
        __builtin_amdgcn_s_setprio(1);
        #pragma unroll
        for (int dblk = 0; dblk < 4; ++dblk)
            oacc[dblk] = __builtin_amdgcn_mfma_f32_32x32x16_bf16(f0.v, vf[0][dblk], oacc[dblk], 0, 0, 0);
        #pragma unroll
        for (int dblk = 0; dblk < 4; ++dblk)
            oacc[dblk] = __builtin_amdgcn_mfma_f32_32x32x16_bf16(f1.v, vf[1][dblk], oacc[dblk], 0, 0, 0);
        __builtin_amdgcn_s_setprio(0);
    };

    STAGE(0, 0);
    int cur = 0;
    for (int t = 0; t < 16; ++t) {
        if (t < 15) {
            STAGE(cur ^ 1, t + 1);
            WAITVN(8);                // my tile-t loads landed; next in flight
        } else {
            WAITVN(0);
        }
        SBAR();
        SUB(cur, 0);
        SUB(cur, 1);
        asm volatile("s_waitcnt lgkmcnt(0)" ::: "memory");
        SBAR();
        cur ^= 1;
    }

    // rowsum[q=r31] = own half + partner half
    const float tot = lsum + __shfl_xor(lsum, 32, 64);
    const float rinv = 1.0f / tot;
    short* ob = O + ((long)b * Nn + q0) * Dd;
    #pragma unroll
    for (int r = 0; r < 16; ++r) {
        const int qq = (r & 3) + 8 * (r >> 2) + 4 * h8;
        const float inv = __shfl(rinv, qq, 64);
        #pragma unroll
        for (int dblk = 0; dblk < 4; ++dblk)
            ob[qq * Dd + dblk * 32 + r31] = (short)f2bf(oacc[dblk][r] * inv);
    }
}

// ---------------------------------------------------------------------------
// Kernel 3: MFMA fc1 + relu + softmax + pooled*w. Grid doubled to 1024
// (64 rows/block) for 2x TLP on the latency-bound fragmented loads.
__global__ __launch_bounds__(256, 2) void k_fuse(const short* __restrict__ d1s,
                                                 const short* __restrict__ d2s,
                                                 const short* __restrict__ layA,
                                                 const short* __restrict__ layB,
                                                 const float* __restrict__ fc1w,
                                                 const float* __restrict__ fc1b,
                                                 float* __restrict__ out) {
    const int tid = threadIdx.x, wave = tid >> 6, lane = tid & 63;
    const int m = lane & 15, g = lane >> 4;

    bf16x8 wb[4][8];
    #pragma unroll
    for (int t = 0; t < 4; ++t)
        #pragma unroll
        for (int c = 0; c < 8; ++c) {
            const float* wp = fc1w + (t * 16 + m) * 256 + c * 32 + g * 8;
            const float4 a = *(const float4*)wp;
            const float4 bq = *(const float4*)(wp + 4);
            union { unsigned u[4]; bf16x8 v; } pk;
            pk.u[0] = cvt_pk_bf16(a.x, a.y);
            pk.u[1] = cvt_pk_bf16(a.z, a.w);
            pk.u[2] = cvt_pk_bf16(bq.x, bq.y);
            pk.u[3] = cvt_pk_bf16(bq.z, bq.w);
            wb[t][c] = pk.v;
        }
    float bias[4];
    #pragma unroll
    for (int t = 0; t < 4; ++t) bias[t] = fc1b[t * 16 + m];

    const int row0 = blockIdx.x * 64 + wave * 16;
    const int bb = row0 >> 11;
    const int i0 = row0 & 2047;
    const bool hf = (i0 >= Nn);
    const int ii = hf ? i0 - Nn : i0;
    const short* dsrc = (hf ? d2s : d1s) + ((long)bb * Nn + ii) * Dd;
    const short* lsrc = (hf ? layB : layA) + ((long)bb * Nn + ii) * Dd;

    f32x4 acc[4];
    #pragma unroll
    for (int t = 0; t < 4; ++t) acc[t] = (f32x4){0.f, 0.f, 0.f, 0.f};
    #pragma unroll
    for (int c = 0; c < 8; ++c) {
        const short* ap = (c < 4)
            ? dsrc + (long)m * Dd + ((c * 32 + g * 8) ^ ((m & 7) * 8))
            : lsrc + (long)m * Dd + (c - 4) * 32 + g * 8;
        const bf16x8 af = *(const bf16x8*)ap;
        #pragma unroll
        for (int t = 0; t < 4; ++t)
            acc[t] = __builtin_amdgcn_mfma_f32_16x16x32_bf16(af, wb[t][c], acc[t], 0, 0, 0);
    }
    #pragma unroll
    for (int r = 0; r < 4; ++r) {
        float v[4];
        #pragma unroll
        for (int t = 0; t < 4; ++t) v[t] = fmaxf(acc[t][r] + bias[t], 0.f);
        float mx = fmaxf(fmaxf(v[0], v[1]), fmaxf(v[2], v[3]));
        #pragma unroll
        for (int msk = 1; msk < 16; msk <<= 1)
            mx = fmaxf(mx, __shfl_xor(mx, msk, 64));
        float e[4], sum = 0.f;
        #pragma unroll
        for (int t = 0; t < 4; ++t) { e[t] = exp2f((v[t] - mx) * LOG2E); sum += e[t]; }
        #pragma unroll
        for (int msk = 1; msk < 16; msk <<= 1) sum += __shfl_xor(sum, msk, 64);
        const float rinv = 1.0f / sum;

        const int rr = 4 * g + r;
        const short* dr = dsrc + (long)rr * Dd;
        const short* lr = lsrc + (long)rr * Dd;
        float pooled[4];
        #pragma unroll
        for (int t = 0; t < 2; ++t) {
            const int e0 = t * 64 + 4 * m;
            const int phys = (((e0 >> 3) ^ (rr & 7)) * 8) + (e0 & 7);
            const short4 s4 = *(const short4*)(dr + phys);
            pooled[t] = 0.25f * (bf2f(s4.x) + bf2f(s4.y) + bf2f(s4.z) + bf2f(s4.w));
        }
        #pragma unroll
        for (int t = 2; t < 4; ++t) {
            const short4 s4 = *(const short4*)(lr + (t - 2) * 64 + 4 * m);
            pooled[t] = 0.25f * (bf2f(s4.x) + bf2f(s4.y) + bf2f(s4.z) + bf2f(s4.w));
        }
        float* op = out + ((long)row0 + rr) * OUTW;
        #pragma unroll
        for (int t = 0; t < 4; ++t) op[t * 16 + m] = pooled[t] * (e[t] * rinv);
    }
}

// ---------------------------------------------------------------------------
extern "C" void kernel_launch(void* const* d_in, const int* in_sizes, int n_in,
                              void* d_out, int out_size, void* d_ws, size_t ws_size,
                              hipStream_t stream) {
    const float* drug1 = (const float*)d_in[0];
    const float* drug2 = (const float*)d_in[1];
    const float* fc1w  = (const float*)d_in[2];
    const float* fc1b  = (const float*)d_in[3];
    float* out = (float*)d_out;

    char* ws = (char*)d_ws;                        // 48 MB total (proven)
    short* d1s    = (short*)(ws);                  //  8 MB swizzled bf16 d1
    short* d2s    = (short*)(ws + 8388608);        //  8 MB swizzled bf16 d2
    short* d1ts   = (short*)(ws + 16777216);       //  8 MB swizzled transposed d1
    short* d2ts   = (short*)(ws + 25165824);       //  8 MB swizzled transposed d2
    short* layerA = (short*)(ws + 33554432);       //  8 MB bf16 drug2_layer
    short* layerB = (short*)(ws + 41943040);       //  8 MB bf16 drug1_layer

    hipLaunchKernelGGL(k_norm, dim3(16, 32, 2), dim3(256), 0, stream,
                       drug1, drug2, d1s, d2s, d1ts, d2ts);
    hipLaunchKernelGGL(k_attn, dim3(512), dim3(256), 0, stream,
                       d1s, d2s, d1ts, d2ts, layerA, layerB);
    hipLaunchKernelGGL(k_fuse, dim3(1024), dim3(256), 0, stream,
                       d1s, d2s, layerA, layerB, fc1w, fc1b, out);
}